// Round 4
// baseline (75.802 us; speedup 1.0000x reference)
//
#include <hip/hip_runtime.h>

// SoftPixelCNN: out[v, o*64+f] = (1/K) * sum_k exp(-A*d[o,v,k]) * feats[nidx[v,k], f]
// d[o,v,k] = ||(c_v + off_o) - c_n||^2 = base + 2*delta.off_o + ||off_o||^2, A = 10*length_scale.
// Offsets (meshgrid-xy order): [0, -e1, -e0, -e2, -e3, +e3, +e2, +e0, +e1].
// NUMERICS: exponentiate the COMBINED exponent (always <= 0); factoring into
// exp(-A*base)*exp(+/-2A*delta_j) gives 0*inf = NaN for far neighbours.
// STRUCTURE (r4): zero LDS. Lane k of the wave holds the 9 weights for neighbor k;
// phase 2 broadcasts via v_readlane (SGPR) feeding v_fmac directly. All 32 feature
// gathers are pinned in flight ahead of the FMA loop via sched_barrier(0).

#define KNB 32
#define FDIM 64
#define ODIM 9

__global__ __launch_bounds__(256) void spcnn_kernel(
    const float* __restrict__ coords,   // (V,4)
    const float* __restrict__ feats,    // (V,64)
    const int*   __restrict__ nidx,     // (V,32)
    const float* __restrict__ lscale,   // (1,)
    float* __restrict__ out)            // (V,576)
{
    const int lane = threadIdx.x & 63;
    const int v = blockIdx.x * 4 + (threadIdx.x >> 6);

    const float A = 10.0f * lscale[0];

    // lane L holds data for neighbor k = L & 31 (both wave halves redundantly)
    const int myidx = nidx[v * KNB + (lane & 31)];

    // ---- phase 1 (all lanes, branchless): 9 weights for my k ----
    float w0, w1, w2, w3, w4, w5, w6, w7, w8;
    {
        const float4 cn = *(const float4*)(coords + (size_t)(unsigned)myidx * 4);
        const float4 cv = *(const float4*)(coords + (size_t)v * 4);
        const float d0 = cv.x - cn.x, d1 = cv.y - cn.y, d2 = cv.z - cn.z, d3 = cv.w - cn.w;
        const float base = d0*d0 + d1*d1 + d2*d2 + d3*d3;

        const float ex_base = -A * base;
        const float bmA = ex_base - A;          // minus A*||off||^2 (=1 for axis offsets)
        const float t0 = 2.0f*A*d0, t1 = 2.0f*A*d1, t2 = 2.0f*A*d2, t3 = 2.0f*A*d3;
        const float s = 1.0f / (float)KNB;      // fold mean-over-K

        w0 = __expf(ex_base)  * s;
        w1 = __expf(bmA + t1) * s;              // o = -e1
        w2 = __expf(bmA + t0) * s;              // o = -e0
        w3 = __expf(bmA + t2) * s;              // o = -e2
        w4 = __expf(bmA + t3) * s;              // o = -e3
        w5 = __expf(bmA - t3) * s;              // o = +e3
        w6 = __expf(bmA - t2) * s;              // o = +e2
        w7 = __expf(bmA - t0) * s;              // o = +e0
        w8 = __expf(bmA - t1) * s;              // o = +e1
    }

    // ---- phase 2: lane = feature f. Pin ALL 32 gathers in flight, then FMA. ----
    float g[KNB];
    #pragma unroll
    for (int k = 0; k < KNB; ++k) {
        const unsigned idx = (unsigned)__builtin_amdgcn_readlane(myidx, k); // SGPR base
        g[k] = feats[(size_t)idx * FDIM + lane];  // saddr + coalesced 256B row
    }
    __builtin_amdgcn_sched_barrier(0);  // do NOT sink the loads into the FMA loop

    float acc0=0.f,acc1=0.f,acc2=0.f,acc3=0.f,acc4=0.f,acc5=0.f,acc6=0.f,acc7=0.f,acc8=0.f;
    #pragma unroll
    for (int k = 0; k < KNB; ++k) {
        // broadcast lane k's weights to SGPRs; v_fmac reads the SGPR directly
        const float s0 = __int_as_float(__builtin_amdgcn_readlane(__float_as_int(w0), k));
        const float s1 = __int_as_float(__builtin_amdgcn_readlane(__float_as_int(w1), k));
        const float s2 = __int_as_float(__builtin_amdgcn_readlane(__float_as_int(w2), k));
        const float s3 = __int_as_float(__builtin_amdgcn_readlane(__float_as_int(w3), k));
        const float s4 = __int_as_float(__builtin_amdgcn_readlane(__float_as_int(w4), k));
        const float s5 = __int_as_float(__builtin_amdgcn_readlane(__float_as_int(w5), k));
        const float s6 = __int_as_float(__builtin_amdgcn_readlane(__float_as_int(w6), k));
        const float s7 = __int_as_float(__builtin_amdgcn_readlane(__float_as_int(w7), k));
        const float s8 = __int_as_float(__builtin_amdgcn_readlane(__float_as_int(w8), k));
        const float gk = g[k];
        acc0 = fmaf(s0, gk, acc0); acc1 = fmaf(s1, gk, acc1); acc2 = fmaf(s2, gk, acc2);
        acc3 = fmaf(s3, gk, acc3); acc4 = fmaf(s4, gk, acc4); acc5 = fmaf(s5, gk, acc5);
        acc6 = fmaf(s6, gk, acc6); acc7 = fmaf(s7, gk, acc7); acc8 = fmaf(s8, gk, acc8);
    }

    float* op = out + (size_t)v * (ODIM * FDIM) + lane;
    op[0*FDIM] = acc0; op[1*FDIM] = acc1; op[2*FDIM] = acc2;
    op[3*FDIM] = acc3; op[4*FDIM] = acc4; op[5*FDIM] = acc5;
    op[6*FDIM] = acc6; op[7*FDIM] = acc7; op[8*FDIM] = acc8;
}

extern "C" void kernel_launch(void* const* d_in, const int* in_sizes, int n_in,
                              void* d_out, int out_size, void* d_ws, size_t ws_size,
                              hipStream_t stream) {
    const float* coords = (const float*)d_in[0];   // (V,4) f32
    const float* feats  = (const float*)d_in[1];   // (V,64) f32
    // d_in[2] = distsq — unused on the inference path
    const int*   nbidx  = (const int*)d_in[3];     // (V,32) i32
    const float* lscale = (const float*)d_in[4];   // (1,) f32

    const int V = in_sizes[0] / 4;                 // 50000
    const int blocks = V / 4;                      // 4 vertices per 256-thread block

    spcnn_kernel<<<blocks, 256, 0, stream>>>(coords, feats, nbidx, lscale, (float*)d_out);
}